// Round 1
// baseline (422.838 us; speedup 1.0000x reference)
//
#include <hip/hip_runtime.h>

// RWKV6 TimeMix on MI355X — R6: fold token-shift mix into weights, fuse the
// four projection GEMMs into ONE GEMM via K-concatenation.
//   (tm*x + (1-tm)*x_prev) @ W^T  ==  x @ (tm.*W)^T + x_prev @ ((1-tm).*W)^T
// so with A_cat = [x | shift(x)] (4096x2048) and W_cat = 4 stacked scaled
// weight pairs (4096x2048), all of r,k,v,w come from a single
// M=4096, N=4096, K=2048 GEMM (vs 4x M=4096,N=1024,K=1024 — which was
// latency-bound at 212 TF / MfmaUtil 8.4%).
//
//   K0 prep_w2    : build W_cat (tm-scaled, bf16) + W_o bf16
//   K1 prep_acat  : build A_cat = [x | shift(x)] bf16
//   K2 gemm_proj  : one MFMA GEMM + per-n-range activations -> r,k,v (bf16), w (fp32)
//   K3 scan_intra : chunked (C=64) scan -> o_intra (fp32), rd (bf16), U_c, D_c
//   K4 state_prop : S_{c+1} = D_c*S_c + U_c (U slot becomes chunk-initial S_c)
//   K5 inter_ln   : O = o_intra + RD@S_c (MFMA), group-LN, *r -> oh (bf16)
//   K6 gemm_out   : MFMA GEMM -> d_out (fp32)
//
// Shapes: B=4, T=1024, D=1024, H=16, DH=64. Chunks: NC=16, C=64.

typedef unsigned short u16;
typedef unsigned int   u32;

typedef __attribute__((ext_vector_type(8))) __bf16 bf16x8;
typedef __attribute__((ext_vector_type(4))) float   f32x4;

#define MB (1u << 20)

#define LDS_PTR(p) ((__attribute__((address_space(3))) void*)(p))
#define GLB_PTR(p) ((const __attribute__((address_space(1))) void*)(p))

__device__ __forceinline__ u16 f2bf(float f) {
  u32 u = __builtin_bit_cast(u32, f);
  u += 0x7FFFu + ((u >> 16) & 1u);   // RNE; inputs are finite
  return (u16)(u >> 16);
}
__device__ __forceinline__ float bf2f(u16 x) {
  u32 u = ((u32)x) << 16;
  return __builtin_bit_cast(float, u);
}
__device__ __forceinline__ u32 pack2(float a, float b) {
  return (u32)f2bf(a) | ((u32)f2bf(b) << 16);
}

// ---------------- K0: W_cat (tm-scaled bf16) + W_o bf16 ---------------------
// W_cat row n (0..4095): sel = n>>10 picks (r,k,v,w); for k<1024 ->
// tm_sel[k]*W_sel[n&1023][k]; for k>=1024 -> (1-tm_sel[k-1024])*W_sel[...].
// One thread: reads one fp32 pair of W once, writes both halves (2 u32).
__global__ __launch_bounds__(256) void prep_w2(
    const float* __restrict__ W_r, const float* __restrict__ W_k,
    const float* __restrict__ W_v, const float* __restrict__ W_w,
    const float* __restrict__ W_o,
    const float* __restrict__ tm_r, const float* __restrict__ tm_k,
    const float* __restrict__ tm_v, const float* __restrict__ tm_w,
    u32* __restrict__ Wcat, u32* __restrict__ Wob) {
  int idx = blockIdx.x * 256 + threadIdx.x;   // 0 .. 2621439
  if (idx < 4096 * 512) {
    int n = idx >> 9, kp = idx & 511;         // n row, kp = k/2
    int sel = n >> 10, nr = n & 1023;
    const float* Wsrc = (sel == 0) ? W_r : (sel == 1) ? W_k : (sel == 2) ? W_v : W_w;
    const float* tm   = (sel == 0) ? tm_r : (sel == 1) ? tm_k : (sel == 2) ? tm_v : tm_w;
    float2 wv = *(const float2*)(Wsrc + (size_t)nr * 1024 + kp * 2);
    float2 t  = *(const float2*)(tm + kp * 2);
    u32* rowp = Wcat + (size_t)n * 1024;      // 2048 bf16 = 1024 u32 per row
    rowp[kp]       = pack2(t.x * wv.x, t.y * wv.y);
    rowp[512 + kp] = pack2((1.f - t.x) * wv.x, (1.f - t.y) * wv.y);
  } else {
    int l = idx - 4096 * 512;                 // 0..524287 pairs of W_o
    float2 v = *(const float2*)(W_o + (size_t)l * 2);
    Wob[l] = pack2(v.x, v.y);
  }
}

// ---------------- K1: A_cat = [x | shift(x)] bf16 ---------------------------
// Thread (m, kp) reads x[m][2kp..2kp+1] once; writes A_cat[m][2kp..] and
// (if t<1023) A_cat[m+1][1024+2kp..]; zeroes A_cat[m][1024+2kp..] when t==0.
__global__ __launch_bounds__(256) void prep_acat(
    const float* __restrict__ x, u32* __restrict__ Acat) {
  int idx = blockIdx.x * 256 + threadIdx.x;   // 4096*512
  int m = idx >> 9, kp = idx & 511;
  float2 v = *(const float2*)(x + (size_t)m * 1024 + kp * 2);
  u32 p = pack2(v.x, v.y);
  u32* row = Acat + (size_t)m * 1024;         // 2048 bf16 = 1024 u32 per row
  row[kp] = p;
  int t = m & 1023;
  if (t < 1023) Acat[(size_t)(m + 1) * 1024 + 512 + kp] = p;
  if (t == 0)   row[512 + kp] = 0;
}

// ---------------- GEMM core: C[m][n] = sum_k A[m][k]*W[n][k] ----------------
// Tile 128x128xBK32, 256 threads, K = KITER*32. Triple-buffered
// global_load_lds pipeline (raw s_barrier + manual vmcnt, never vmcnt(0) in
// steady state). XOR-swizzled LDS.
//   MODE 0: plain fp32 store to o0 (N=1024 output)
//   MODE 1: fused projection epilogue — n in [0,4096), mat = n>>10 selects
//           {r: sigmoid->bf16, k: bf16, v: bf16, w: -softplus(-z)-1e-4 fp32},
//           column = n & 1023. mat is uniform per block (n-tile is 128-wide).
template <int KITER, int MODE>
__device__ __forceinline__ void gemm_core(
    const u16* __restrict__ A, const u16* __restrict__ W,
    void* __restrict__ o0, void* __restrict__ o1,
    void* __restrict__ o2, void* __restrict__ o3,
    u16* Asm, u16* Bsm) {   // each 3*4096 u16 (3 x 8KB)
  constexpr int LDK = KITER * 32;
  int tid = threadIdx.x;
  int m0 = blockIdx.x * 128, n0 = blockIdx.y * 128;
  int wave = tid >> 6, lane = tid & 63;
  int wm = (wave >> 1) * 64, wn = (wave & 1) * 64;
  int r16 = lane & 15, quad = lane >> 4;

  f32x4 acc[4][4] = {};

  int srow0 = wave * 32 + (lane >> 2);
  int srow1 = srow0 + 16;
  int c4    = lane & 3;
  int q0 = c4 ^ ((srow0 >> 1) & 3);
  int q1 = c4 ^ ((srow1 >> 1) & 3);
  const u16* Ag0 = A + (size_t)(m0 + srow0) * LDK + q0 * 8;
  const u16* Ag1 = A + (size_t)(m0 + srow1) * LDK + q1 * 8;
  const u16* Bg0 = W + (size_t)(n0 + srow0) * LDK + q0 * 8;
  const u16* Bg1 = W + (size_t)(n0 + srow1) * LDK + q1 * 8;
  int ldsOff0 = wave * 1024;        // u16 offset within one 8KB buffer
  int ldsOff1 = wave * 1024 + 512;

  int aoff[4], boff[4];
#pragma unroll
  for (int mt = 0; mt < 4; ++mt) {
    int r = wm + mt * 16 + r16;
    aoff[mt] = r * 32 + (quad ^ ((r >> 1) & 3)) * 8;
  }
#pragma unroll
  for (int nt = 0; nt < 4; ++nt) {
    int r = wn + nt * 16 + r16;
    boff[nt] = r * 32 + (quad ^ ((r >> 1) & 3)) * 8;
  }

#define ISSUE_TILE(t, buf)                                                              \
  do {                                                                                  \
    int _o = (buf) * 4096, _k = (t) * 32;                                               \
    __builtin_amdgcn_global_load_lds(GLB_PTR(Ag0 + _k), LDS_PTR(Asm + _o + ldsOff0), 16, 0, 0); \
    __builtin_amdgcn_global_load_lds(GLB_PTR(Ag1 + _k), LDS_PTR(Asm + _o + ldsOff1), 16, 0, 0); \
    __builtin_amdgcn_global_load_lds(GLB_PTR(Bg0 + _k), LDS_PTR(Bsm + _o + ldsOff0), 16, 0, 0); \
    __builtin_amdgcn_global_load_lds(GLB_PTR(Bg1 + _k), LDS_PTR(Bsm + _o + ldsOff1), 16, 0, 0); \
  } while (0)

  ISSUE_TILE(0, 0);
  ISSUE_TILE(1, 1);
  ISSUE_TILE(2, 2);

  int cur = 0;
  for (int i = 0; i < KITER; ++i) {
    if (i < KITER - 2)       asm volatile("s_waitcnt vmcnt(8)" ::: "memory");
    else if (i == KITER - 2) asm volatile("s_waitcnt vmcnt(4)" ::: "memory");
    else                     asm volatile("s_waitcnt vmcnt(0)" ::: "memory");
    __builtin_amdgcn_s_barrier();   // all waves' tile-i data landed

    const u16* As = Asm + cur * 4096;
    const u16* Bs = Bsm + cur * 4096;
    bf16x8 af[4], bfm[4];
#pragma unroll
    for (int mt = 0; mt < 4; ++mt) af[mt] = *(const bf16x8*)&As[aoff[mt]];
#pragma unroll
    for (int nt = 0; nt < 4; ++nt) bfm[nt] = *(const bf16x8*)&Bs[boff[nt]];
#pragma unroll
    for (int mt = 0; mt < 4; ++mt)
#pragma unroll
      for (int nt = 0; nt < 4; ++nt)
        acc[mt][nt] = __builtin_amdgcn_mfma_f32_16x16x32_bf16(af[mt], bfm[nt], acc[mt][nt], 0, 0, 0);

    asm volatile("s_waitcnt lgkmcnt(0)" ::: "memory");  // my ds_reads done
    __builtin_amdgcn_s_barrier();                       // everyone's reads done
    if (i + 3 < KITER) ISSUE_TILE(i + 3, cur);          // re-target freed buffer
    cur = (cur == 2) ? 0 : cur + 1;
  }
#undef ISSUE_TILE

  // epilogue: C/D layout col=lane&15, row=quad*4+reg  [verified m89/m91]
  int mat  = n0 >> 10;          // uniform per block (MODE 1)
  int colb = n0 & 1023;
#pragma unroll
  for (int mt = 0; mt < 4; ++mt) {
#pragma unroll
    for (int nt = 0; nt < 4; ++nt) {
#pragma unroll
      for (int rg = 0; rg < 4; ++rg) {
        int row = m0 + wm + mt * 16 + quad * 4 + rg;
        float v = acc[mt][nt][rg];
        if (MODE == 0) {
          int col = n0 + wn + nt * 16 + r16;
          ((float*)o0)[(size_t)row * 1024 + col] = v;
        } else {
          int col = colb + wn + nt * 16 + r16;
          size_t idx = (size_t)row * 1024 + col;
          if (mat == 0) {          // r = sigmoid -> bf16
            ((u16*)o0)[idx] = f2bf(1.f / (1.f + __expf(-v)));
          } else if (mat == 1) {   // k -> bf16
            ((u16*)o1)[idx] = f2bf(v);
          } else if (mat == 2) {   // v -> bf16
            ((u16*)o2)[idx] = f2bf(v);
          } else {                 // w = -softplus(-z) - 1e-4 -> fp32
            ((float*)o3)[idx] = -(fmaxf(-v, 0.f) + log1pf(expf(-fabsf(v)))) - 1e-4f;
          }
        }
      }
    }
  }
}

// K2: single fused projection GEMM (M=4096, N=4096, K=2048)
__global__ __launch_bounds__(256) void gemm_proj(
    const u16* __restrict__ A, const u16* __restrict__ W,
    u16* __restrict__ r, u16* __restrict__ k,
    u16* __restrict__ v, float* __restrict__ w) {
  __shared__ __align__(16) u16 Asm[3 * 4096];
  __shared__ __align__(16) u16 Bsm[3 * 4096];
  gemm_core<64, 1>(A, W, r, k, v, w, Asm, Bsm);
}

// K6: output GEMM (M=4096, N=1024, K=1024)
__global__ __launch_bounds__(256) void gemm_out(
    const u16* __restrict__ A, const u16* __restrict__ W, float* __restrict__ O) {
  __shared__ __align__(16) u16 Asm[3 * 4096];
  __shared__ __align__(16) u16 Bsm[3 * 4096];
  gemm_core<32, 0>(A, W, O, nullptr, nullptr, nullptr, Asm, Bsm);
}

// ---------------- K3: single-pass intra-chunk scan (2-step batching) --------
// Block = (chunk c, b*16+h), 256 threads = 4 i-groups x 64 j.
// Loader roles: w0 -> r (and rd/decay), w1 -> k(+euk), w2 -> v, w3 -> ew.
// 4-slot LDS ring (slot = t&3): stage steps tt+2,tt+3 while computing tt,tt+1.
// One barrier per 2 steps. o-stores deferred one interval (part slots).
__global__ __launch_bounds__(256) void scan_intra(
    const u16* __restrict__ rb, const u16* __restrict__ kb,
    const u16* __restrict__ vb, const float* __restrict__ wb,
    const float* __restrict__ u,
    float* __restrict__ o, u16* __restrict__ rd,
    float* __restrict__ U, float* __restrict__ Dc) {
  int c = blockIdx.x, bh = blockIdx.y;
  int b = bh >> 4, h = bh & 15;
  int tid = threadIdx.x, ig = tid >> 6, j = tid & 63;

  __shared__ __align__(16) float4 combo[4][64];  // per-i: (r, k, exp(u+k), exp(w))
  __shared__ float vs_[4][64];
  __shared__ float part[4][4][64];

  float s[16];
#pragma unroll
  for (int ii = 0; ii < 16; ++ii) s[ii] = 0.f;

  size_t base = ((size_t)(b * 1024 + c * 64)) * 1024 + h * 64 + j;
  float dloc = 1.0f;
  float uval = (ig == 1) ? u[h * 64 + j] : 0.f;

  // prologue: stage steps 0,1 into slots 0,1
#pragma unroll
  for (int p = 0; p < 2; ++p) {
    size_t idx = base + (size_t)p * 1024;
    if (ig == 0)      combo[p][j].x = bf2f(rb[idx]);
    else if (ig == 1) { float kv = bf2f(kb[idx]); combo[p][j].y = kv; combo[p][j].z = __expf(uval + kv); }
    else if (ig == 2) vs_[p][j] = bf2f(vb[idx]);
    else              combo[p][j].w = __expf(wb[idx]);
  }
  __syncthreads();

  for (int tt = 0; tt < 64; tt += 2) {
    // stage steps tt+2, tt+3 into their slots (disjoint from compute slots)
    if (tt + 2 < 64) {
#pragma unroll
      for (int p = 0; p < 2; ++p) {
        int t2 = tt + 2 + p, sl = t2 & 3;
        size_t idx = base + (size_t)t2 * 1024;
        if (ig == 0)      combo[sl][j].x = bf2f(rb[idx]);
        else if (ig == 1) { float kv = bf2f(kb[idx]); combo[sl][j].y = kv; combo[sl][j].z = __expf(uval + kv); }
        else if (ig == 2) vs_[sl][j] = bf2f(vb[idx]);
        else              combo[sl][j].w = __expf(wb[idx]);
      }
    }
    // compute steps tt, tt+1 (slots staged last interval, barrier crossed)
#pragma unroll
    for (int p = 0; p < 2; ++p) {
      int t = tt + p, sl = t & 3;
      float vj = vs_[sl][j];
      float acc = 0.f;
#pragma unroll
      for (int ii = 0; ii < 16; ++ii) {
        float4 cb = combo[sl][ig * 16 + ii];  // broadcast b128
        float tmp = fmaf(cb.z, vj, s[ii]);    // s + exp(u+k)*v
        acc = fmaf(cb.x, tmp, acc);           // += r * (...)
        s[ii] = fmaf(cb.w, s[ii], cb.y * vj); // s = exp(w)*s + k*v
      }
      part[sl][ig][j] = acc;
      if (ig == 0) {
        rd[base + (size_t)t * 1024] = f2bf(combo[sl][j].x * dloc);
        dloc *= combo[sl][j].w;
      }
    }
    // store o for steps tt-2, tt-1 (parts complete since last barrier)
    if (tt >= 2) {
      if (ig == 2) {
        int t = tt - 2, sl = t & 3;
        o[base + (size_t)t * 1024] =
            part[sl][0][j] + part[sl][1][j] + part[sl][2][j] + part[sl][3][j];
      } else if (ig == 3) {
        int t = tt - 1, sl = t & 3;
        o[base + (size_t)t * 1024] =
            part[sl][0][j] + part[sl][1][j] + part[sl][2][j] + part[sl][3][j];
      }
    }
    __syncthreads();
  }
  // final two steps' o (parts written in last interval, barrier crossed)
  if (ig == 2) {
    o[base + (size_t)62 * 1024] = part[2][0][j] + part[2][1][j] + part[2][2][j] + part[2][3][j];
  } else if (ig == 3) {
    o[base + (size_t)63 * 1024] = part[3][0][j] + part[3][1][j] + part[3][2][j] + part[3][3][j];
  }

  float* Ug = U + (size_t)(bh * 16 + c) * 4096;
#pragma unroll
  for (int ii = 0; ii < 16; ++ii) Ug[(ig * 16 + ii) * 64 + j] = s[ii];
  if (ig == 0) Dc[(bh * 16 + c) * 64 + j] = dloc;
}

// ---------------- K4: chunk-state propagation (per-element parallel) --------
__global__ __launch_bounds__(256) void state_prop(
    float* __restrict__ U, const float* __restrict__ Dc) {
  int bh  = blockIdx.x >> 4;
  int e   = (blockIdx.x & 15) * 256 + threadIdx.x;  // 0..4095
  int i   = e >> 6;                                 // state row (decay index)
  float acc = 0.f;
  for (int c = 0; c < 16; ++c) {
    float* Ug = U + (size_t)(bh * 16 + c) * 4096 + e;
    float d = Dc[(bh * 16 + c) * 64 + i];
    float uv = *Ug;
    *Ug = acc;                      // write S_c (chunk-initial state)
    acc = fmaf(d, acc, uv);         // S_{c+1} = D_c*S_c + U_c
  }
}

// ---------------- K5: O = o_intra + RD@S_c (MFMA) + group-LN + gate --------
// Block (c, bh), 256 threads = 4 waves. Wave w owns t-strip [w*16, w*16+16).
// S_c (fp32, [i][j]) transposed to bf16 LDS Sb[j][i] (pad 72 for b128 align).
// A = rd[t][i] (bf16, global, K-contiguous). D[m=t][n=j] = sum_i rd*S.
__global__ __launch_bounds__(256) void inter_ln(
    const float* __restrict__ o, const u16* __restrict__ rd,
    const u16* __restrict__ rb, const float* __restrict__ U,
    const float* __restrict__ lnw, const float* __restrict__ lnb,
    u16* __restrict__ oh) {
  int c = blockIdx.x, bh = blockIdx.y;
  int b = bh >> 4, h = bh & 15;
  int tid = threadIdx.x, wave = tid >> 6, lane = tid & 63;
  int l15 = lane & 15, quad = lane >> 4;

  __shared__ __align__(16) u16 Sb[64][72];   // Sb[j][i] = S_c[i][j] (bf16)

  const float* Sg = U + (size_t)(bh * 16 + c) * 4096;
#pragma unroll
  for (int q = 0; q < 16; ++q) {
    int e = q * 256 + tid;
    Sb[e & 63][e >> 6] = f2bf(Sg[e]);
  }
  __syncthreads();

  size_t rbase = ((size_t)(b * 1024 + c * 64)) * 1024 + h * 64;

  // A fragments: A[m=l15][k=quad*8+idx] (+32 for kt=1), m-strip = wave*16
  const u16* rdg = rd + rbase + (size_t)(wave * 16 + l15) * 1024 + quad * 8;
  bf16x8 af0 = *(const bf16x8*)(rdg);
  bf16x8 af1 = *(const bf16x8*)(rdg + 32);

  f32x4 acc[4] = {};
#pragma unroll
  for (int nt = 0; nt < 4; ++nt) {
    const u16* bp = &Sb[nt * 16 + l15][quad * 8];
    bf16x8 b0 = *(const bf16x8*)bp;
    bf16x8 b1 = *(const bf16x8*)(bp + 32);
    acc[nt] = __builtin_amdgcn_mfma_f32_16x16x32_bf16(af0, b0, acc[nt], 0, 0, 0);
    acc[nt] = __builtin_amdgcn_mfma_f32_16x16x32_bf16(af1, b1, acc[nt], 0, 0, 0);
  }

  // epilogue: row t = wave*16 + quad*4 + rg; col j = nt*16 + l15.
#pragma unroll
  for (int rg = 0; rg < 4; ++rg) {
    int t = wave * 16 + quad * 4 + rg;
    size_t rowb = rbase + (size_t)t * 1024;
    float v[4];
    float s1 = 0.f, s2 = 0.f;
#pragma unroll
    for (int nt = 0; nt < 4; ++nt) {
      v[nt] = acc[nt][rg] + o[rowb + nt * 16 + l15];
      s1 += v[nt];
      s2 += v[nt] * v[nt];
    }
#pragma unroll
    for (int m = 1; m < 16; m <<= 1) {   // reduce across the quad's 16 lanes
      s1 += __shfl_xor(s1, m, 64);
      s2 += __shfl_xor(s2, m, 64);
    }
    float mu  = s1 * (1.f / 64.f);
    float var = s2 * (1.f / 64.f) - mu * mu;
    float rstd = rsqrtf(var + 1e-5f);
#pragma unroll
    for (int nt = 0; nt < 4; ++nt) {
      int jj = nt * 16 + l15;
      float nv = (v[nt] - mu) * rstd;
      float val = (nv * lnw[jj] + lnb[jj]) * bf2f(rb[rowb + jj]);
      oh[rowb + jj] = f2bf(val);
    }
  }
}

// ---------------- launch -----------------------------------------------------
extern "C" void kernel_launch(void* const* d_in, const int* in_sizes, int n_in,
                              void* d_out, int out_size, void* d_ws, size_t ws_size,
                              hipStream_t stream) {
  const float* x    = (const float*)d_in[0];
  const float* W_r  = (const float*)d_in[1];
  const float* W_k  = (const float*)d_in[2];
  const float* W_v  = (const float*)d_in[3];
  const float* W_w  = (const float*)d_in[4];
  const float* W_o  = (const float*)d_in[5];
  const float* u    = (const float*)d_in[6];
  const float* tm_r = (const float*)d_in[7];
  const float* tm_k = (const float*)d_in[8];
  const float* tm_v = (const float*)d_in[9];
  const float* tm_w = (const float*)d_in[10];
  const float* ln_w = (const float*)d_in[11];
  const float* ln_b = (const float*)d_in[12];
  float* out = (float*)d_out;

  char* ws = (char*)d_ws;
  u16*   Acat  = (u16*)(ws + (size_t)0   * MB);  // 16MB  4096x2048 bf16
  u16*   Wcat  = (u16*)(ws + (size_t)16  * MB);  // 16MB  4096x2048 bf16
  u16*   Wob   = (u16*)(ws + (size_t)32  * MB);  // 2MB   1024x1024 bf16
  u16*   rbuf  = (u16*)(ws + (size_t)40  * MB);  // 8MB bf16
  u16*   kbuf  = (u16*)(ws + (size_t)48  * MB);  // 8MB bf16
  u16*   vbuf  = (u16*)(ws + (size_t)56  * MB);  // 8MB bf16
  float* wbuf  = (float*)(ws + (size_t)64 * MB); // 16MB fp32 (decay path)
  float* obuf  = (float*)(ws + (size_t)80 * MB); // 16MB fp32 o_intra
  u16*   rdbuf = (u16*)(ws + (size_t)96 * MB);   // 8MB bf16
  float* Ubuf  = (float*)(ws + (size_t)104 * MB);// 16MB (S_c after state_prop)
  float* Dcbuf = (float*)(ws + (size_t)120 * MB);// 256KB
  u16*   ohbuf = (u16*)(ws + (size_t)121 * MB);  // 8MB

  prep_w2<<<10240, 256, 0, stream>>>(W_r, W_k, W_v, W_w, W_o,
                                     tm_r, tm_k, tm_v, tm_w,
                                     (u32*)Wcat, (u32*)Wob);
  prep_acat<<<8192, 256, 0, stream>>>(x, (u32*)Acat);
  gemm_proj<<<dim3(32, 32), 256, 0, stream>>>(Acat, Wcat,
                                              rbuf, kbuf, vbuf, wbuf);
  scan_intra<<<dim3(16, 64), 256, 0, stream>>>(rbuf, kbuf, vbuf, wbuf, u,
                                               obuf, rdbuf, Ubuf, Dcbuf);
  state_prop<<<1024, 256, 0, stream>>>(Ubuf, Dcbuf);
  inter_ln<<<dim3(16, 64), 256, 0, stream>>>(obuf, rdbuf, rbuf, Ubuf,
                                             ln_w, ln_b, ohbuf);
  gemm_out<<<dim3(32, 8, 1), 256, 0, stream>>>(ohbuf, Wob, out);
}